// Round 6
// baseline (1010.346 us; speedup 1.0000x reference)
//
#include <hip/hip_runtime.h>

#define NB 4
#define SEQ 4096
#define DM 1024
#define DF 64
#define BQ 32     // q rows per attention block
#define BK 64     // keys per tile
#define QSTR 68   // padded LDS strides (floats)
#define KSTR 68
#define VSTR 64
#define PSTR 68

typedef unsigned short u16;
typedef unsigned int u32;

__device__ __forceinline__ float bf2f(u16 u) {
    union { u32 i; float f; } v; v.i = ((u32)u) << 16; return v.f;
}
__device__ __forceinline__ u16 f2bf(float f) {
    union { float f; u32 i; } v; v.f = f;
    u32 lsb = (v.i >> 16) & 1u;
    v.i += 0x7fffu + lsb;          // round-to-nearest-even
    return (u16)(v.i >> 16);
}

// ---------------- Projection: O[r][f] = sum_m X[r][m]*W[f][m] + b[f] --------
// grid 4096, block 256; 4 rows per block staged to LDS; thread (r=t&3, f=t>>2)
// computes the full 1024-length dot. Output bf16 into workspace.
__global__ __launch_bounds__(256) void proj_kernel(
    const float* __restrict__ X, const float* __restrict__ W,
    const float* __restrict__ bias, u16* __restrict__ O)
{
    __shared__ float xs[4 * DM];
    const int t = threadIdx.x;
    const long row0 = (long)blockIdx.x * 4;
    const float4* src = (const float4*)(X + row0 * DM);
#pragma unroll
    for (int c = 0; c < 4; ++c)
        ((float4*)xs)[c * 256 + t] = src[c * 256 + t];
    __syncthreads();

    const int r = t & 3;
    const int f = t >> 2;
    const float4* wrow = (const float4*)(W + (long)f * DM);
    const float4* xrow = (const float4*)(xs + r * DM);
    float acc = 0.f;
#pragma unroll 8
    for (int i = 0; i < DM / 4; ++i) {
        float4 w4 = wrow[i];
        float4 x4 = xrow[i];
        acc += x4.x * w4.x + x4.y * w4.y + x4.z * w4.z + x4.w * w4.w;
    }
    O[(row0 + r) * DF + f] = f2bf(acc + bias[f]);
}

// ---------------- Flash attention (LDS-only communication), fp32 output -----
// grid (128, 4), block 256. Thread (qr = t>>3 in 0..31, kc = t&7 in 0..7):
// scores for 8 keys j = kc+8*jj; row max/sum via LDS partials; P via LDS;
// thread owns output features f = kc*8 .. kc*8+7.
__global__ __launch_bounds__(256) void attn_kernel(
    const u16* __restrict__ Q, const u16* __restrict__ K, const u16* __restrict__ V,
    float* __restrict__ out)
{
    __shared__ float qs[BQ * QSTR];
    __shared__ float ks[BK * KSTR];
    __shared__ float vs[BK * VSTR];
    __shared__ float ps[BQ * PSTR];
    __shared__ float redm[BQ * 8];
    __shared__ float reds[BQ * 8];

    const int t  = threadIdx.x;
    const int b  = blockIdx.y;
    const int q0 = blockIdx.x * BQ;
    const int qr = t >> 3;   // 0..31
    const int kc = t & 7;    // 0..7

    {   // stage Q tile (32 x 64), pre-scaled by 1/sqrt(64)=0.125
        const ushort4* src = (const ushort4*)(Q + (long)(b * SEQ + q0) * DF);
#pragma unroll
        for (int c = 0; c < 2; ++c) {
            int idx  = c * 256 + t;
            int row  = idx >> 4;
            int col4 = idx & 15;
            ushort4 h = src[idx];
            float4 fv;
            fv.x = bf2f(h.x) * 0.125f; fv.y = bf2f(h.y) * 0.125f;
            fv.z = bf2f(h.z) * 0.125f; fv.w = bf2f(h.w) * 0.125f;
            *(float4*)&qs[row * QSTR + col4 * 4] = fv;
        }
    }

    float mrow = -1e30f, lrow = 0.f;
    float o[8];
#pragma unroll
    for (int i = 0; i < 8; ++i) o[i] = 0.f;

    const ushort4* kb = (const ushort4*)(K + (long)b * SEQ * DF);
    const ushort4* vb = (const ushort4*)(V + (long)b * SEQ * DF);

    for (int tile = 0; tile < SEQ / BK; ++tile) {
        __syncthreads();   // prior tile's readers done
#pragma unroll
        for (int c = 0; c < 4; ++c) {      // stage K (padded) + V (flat)
            int idx  = c * 256 + t;        // 0..1023 ushort4 over 64x64
            int row  = idx >> 4;
            int col4 = idx & 15;
            ushort4 hk = kb[tile * 1024 + idx];
            float4 fk;
            fk.x = bf2f(hk.x); fk.y = bf2f(hk.y); fk.z = bf2f(hk.z); fk.w = bf2f(hk.w);
            *(float4*)&ks[row * KSTR + col4 * 4] = fk;
            ushort4 hv = vb[tile * 1024 + idx];
            float4 fv;
            fv.x = bf2f(hv.x); fv.y = bf2f(hv.y); fv.z = bf2f(hv.z); fv.w = bf2f(hv.w);
            *(float4*)&vs[row * VSTR + col4 * 4] = fv;
        }
        __syncthreads();   // staging visible

        float sc[8];
#pragma unroll
        for (int jj = 0; jj < 8; ++jj) {
            int j = kc + 8 * jj;
            float a = 0.f;
#pragma unroll
            for (int f4 = 0; f4 < 16; ++f4) {
                float4 qv = *(const float4*)&qs[qr * QSTR + f4 * 4];
                float4 kv = *(const float4*)&ks[j * KSTR + f4 * 4];
                a += qv.x * kv.x + qv.y * kv.y + qv.z * kv.z + qv.w * kv.w;
            }
            sc[jj] = a;
        }

        float pmx = sc[0];
#pragma unroll
        for (int jj = 1; jj < 8; ++jj) pmx = fmaxf(pmx, sc[jj]);
        redm[qr * 8 + kc] = pmx;
        __syncthreads();
        float tmx = redm[qr * 8 + 0];
#pragma unroll
        for (int i = 1; i < 8; ++i) tmx = fmaxf(tmx, redm[qr * 8 + i]);
        float mn = fmaxf(mrow, tmx);

        float psum = 0.f;
#pragma unroll
        for (int jj = 0; jj < 8; ++jj) {
            float p = __expf(sc[jj] - mn);
            ps[qr * PSTR + kc + 8 * jj] = p;
            psum += p;
        }
        reds[qr * 8 + kc] = psum;
        __syncthreads();   // ps and reds visible
        float tsum = 0.f;
#pragma unroll
        for (int i = 0; i < 8; ++i) tsum += reds[qr * 8 + i];

        float al = __expf(mrow - mn);
        lrow = lrow * al + tsum;
        mrow = mn;
#pragma unroll
        for (int i = 0; i < 8; ++i) o[i] *= al;

        // PV: o[f] += sum_j p[qr][j] * vs[j][kc*8 + f]
#pragma unroll 8
        for (int j = 0; j < 64; ++j) {
            float p = ps[qr * PSTR + j];
            float4 v0 = *(const float4*)&vs[j * VSTR + kc * 8];
            float4 v1 = *(const float4*)&vs[j * VSTR + kc * 8 + 4];
            o[0] += p * v0.x; o[1] += p * v0.y; o[2] += p * v0.z; o[3] += p * v0.w;
            o[4] += p * v1.x; o[5] += p * v1.y; o[6] += p * v1.z; o[7] += p * v1.w;
        }
    }

    // fp32 output (reference output dtype is float32)
    float il = 1.f / lrow;
    long base = (long)(b * SEQ + q0 + qr) * DF + kc * 8;
    float4 w0, w1;
    w0.x = o[0] * il; w0.y = o[1] * il; w0.z = o[2] * il; w0.w = o[3] * il;
    w1.x = o[4] * il; w1.y = o[5] * il; w1.z = o[6] * il; w1.w = o[7] * il;
    *(float4*)&out[base]     = w0;
    *(float4*)&out[base + 4] = w1;
}

extern "C" void kernel_launch(void* const* d_in, const int* in_sizes, int n_in,
                              void* d_out, int out_size, void* d_ws, size_t ws_size,
                              hipStream_t stream) {
    (void)in_sizes; (void)n_in; (void)out_size; (void)ws_size;

    const float* X[3]  = { (const float*)d_in[0], (const float*)d_in[1], (const float*)d_in[2] };
    const float* W[3]  = { (const float*)d_in[3], (const float*)d_in[5], (const float*)d_in[7] };
    const float* Bv[3] = { (const float*)d_in[4], (const float*)d_in[6], (const float*)d_in[8] };

    u16* ws = (u16*)d_ws;
    const size_t proj_elems = (size_t)NB * SEQ * DF;   // 1,048,576
    u16* P[3] = { ws, ws + proj_elems, ws + 2 * proj_elems };  // Q, K, V (bf16)
    float* out = (float*)d_out;

    for (int i = 0; i < 3; ++i)
        proj_kernel<<<(NB * SEQ) / 4, 256, 0, stream>>>(X[i], W[i], Bv[i], P[i]);

    dim3 agrid(SEQ / BQ, NB);
    attn_kernel<<<agrid, 256, 0, stream>>>(P[0], P[1], P[2], out);
}

// Round 7
// 419.713 us; speedup vs baseline: 2.4072x; 2.4072x over previous
//
#include <hip/hip_runtime.h>

#define NB 4
#define SEQ 4096
#define DM 1024
#define DF 64

typedef unsigned short u16;
typedef unsigned int u32;
typedef __attribute__((ext_vector_type(8))) short short8;   // 8 bf16 = 4 VGPR (MFMA A/B frag)
typedef __attribute__((ext_vector_type(4))) float f32x4;    // MFMA C/D frag

__device__ __forceinline__ float bf2f(u16 u) {
    union { u32 i; float f; } v; v.i = ((u32)u) << 16; return v.f;
}
__device__ __forceinline__ u16 f2bf(float f) {
    union { float f; u32 i; } v; v.f = f;
    u32 lsb = (v.i >> 16) & 1u;
    v.i += 0x7fffu + lsb;          // RNE
    return (u16)(v.i >> 16);
}

// ---------------- Projection v2: register-tiled fp32 GEMM -------------------
// C[64 rows x 64 f] per block, 4x4 per thread, K-steps of 32 with transposed
// LDS staging (xt[k][row], wt[k][f]) so inner loop is float4 reads + 16 FMA.
#define XTS 68   // padded stride (floats); 4*tr reads -> 2-way (free)
__global__ __launch_bounds__(256) void proj2_kernel(
    const float* __restrict__ X, const float* __restrict__ W,
    const float* __restrict__ bias, u16* __restrict__ O)
{
    __shared__ float xt[32 * XTS];
    __shared__ float wt[32 * XTS];
    const int t  = threadIdx.x;
    const long r0 = (long)blockIdx.x * 64;

    const int tr = t & 15;    // row group: rows 4tr..4tr+3
    const int tc = t >> 4;    // col group: cols 4tc..4tc+3
    float acc[4][4];
#pragma unroll
    for (int i = 0; i < 4; ++i)
#pragma unroll
        for (int j = 0; j < 4; ++j) acc[i][j] = 0.f;

    const int srow = t >> 2;          // staging row 0..63 (also f index for W)
    const int skq  = (t & 3) << 1;    // staging float4-k base (0,2,4,6)

    for (int k0 = 0; k0 < DM; k0 += 32) {
        __syncthreads();   // prior K-step's readers done
#pragma unroll
        for (int i = 0; i < 2; ++i) {
            int kq = skq + i;                          // 0..7
            float4 xv = *(const float4*)(X + (r0 + srow) * DM + k0 + 4 * kq);
            xt[(4 * kq + 0) * XTS + srow] = xv.x;
            xt[(4 * kq + 1) * XTS + srow] = xv.y;
            xt[(4 * kq + 2) * XTS + srow] = xv.z;
            xt[(4 * kq + 3) * XTS + srow] = xv.w;
            float4 wv = *(const float4*)(W + (long)srow * DM + k0 + 4 * kq);
            wt[(4 * kq + 0) * XTS + srow] = wv.x;
            wt[(4 * kq + 1) * XTS + srow] = wv.y;
            wt[(4 * kq + 2) * XTS + srow] = wv.z;
            wt[(4 * kq + 3) * XTS + srow] = wv.w;
        }
        __syncthreads();   // staging visible
#pragma unroll
        for (int k = 0; k < 32; ++k) {
            float4 a = *(const float4*)&xt[k * XTS + 4 * tr];
            float4 b = *(const float4*)&wt[k * XTS + 4 * tc];
            acc[0][0] += a.x * b.x; acc[0][1] += a.x * b.y; acc[0][2] += a.x * b.z; acc[0][3] += a.x * b.w;
            acc[1][0] += a.y * b.x; acc[1][1] += a.y * b.y; acc[1][2] += a.y * b.z; acc[1][3] += a.y * b.w;
            acc[2][0] += a.z * b.x; acc[2][1] += a.z * b.y; acc[2][2] += a.z * b.z; acc[2][3] += a.z * b.w;
            acc[3][0] += a.w * b.x; acc[3][1] += a.w * b.y; acc[3][2] += a.w * b.z; acc[3][3] += a.w * b.w;
        }
    }

    float4 b4 = *(const float4*)(bias + 4 * tc);
#pragma unroll
    for (int i = 0; i < 4; ++i) {
        ushort4 o;
        o.x = f2bf(acc[i][0] + b4.x); o.y = f2bf(acc[i][1] + b4.y);
        o.z = f2bf(acc[i][2] + b4.z); o.w = f2bf(acc[i][3] + b4.w);
        *(ushort4*)&O[(r0 + 4 * tr + i) * DF + 4 * tc] = o;
    }
}

// ---------------- MFMA flash attention --------------------------------------
// grid (64, 4), block 256 (4 waves). Block covers 64 q rows; wave w owns
// q rows q0+16w..+15. 64-key tiles: QK^T and PV via 16x16x32 bf16 MFMA.
// A-frag: A[m=lane&15][k=quad*8+j]; B-frag: B[k=quad*8+j][n=lane&15];
// C/D: col=lane&15, row=quad*4+reg  [per guide §3, HW-verified].
#define KSTR 72          // padded LDS stride (shorts), keeps 16B align
#define MFMA16(a, b, c) __builtin_amdgcn_mfma_f32_16x16x32_bf16(a, b, c, 0, 0, 0)

__global__ __launch_bounds__(256) void attn_mfma_kernel(
    const u16* __restrict__ Qg, const u16* __restrict__ Kg, const u16* __restrict__ Vg,
    float* __restrict__ out)
{
    __shared__ u16 ks[64 * KSTR];        // K tile, row-major [key][d]
    __shared__ u16 vt[64 * KSTR];        // V tile TRANSPOSED [f][key]
    __shared__ u16 ps[4][16 * KSTR];     // per-wave P tile [q][key]

    const int t    = threadIdx.x;
    const int w    = t >> 6;
    const int lane = t & 63;
    const int m15  = lane & 15;
    const int quad = lane >> 4;
    const int b    = blockIdx.y;
    const int q0   = blockIdx.x * 64;

    // Q fragments, resident for the whole kernel (direct from global, bf16)
    const u16* qptr = Qg + ((long)(b * SEQ + q0 + 16 * w + m15)) * DF + quad * 8;
    short8 qa0 = *(const short8*)qptr;          // d 0..31 chunk
    short8 qa1 = *(const short8*)(qptr + 32);   // d 32..63 chunk

    f32x4 accO[4];
#pragma unroll
    for (int F = 0; F < 4; ++F) accO[F] = (f32x4){0.f, 0.f, 0.f, 0.f};
    float mrow[4] = {-1e30f, -1e30f, -1e30f, -1e30f};
    float lrow[4] = {0.f, 0.f, 0.f, 0.f};

    const ushort4* kb4 = (const ushort4*)(Kg + (long)b * SEQ * DF);
    const ushort4* vb4 = (const ushort4*)(Vg + (long)b * SEQ * DF);

    // staging registers (software pipeline: global->reg ahead, reg->LDS at top)
    ushort4 kreg[4], vreg[4];
    const int krow  = t >> 4;          // K staging: rows krow, krow+16,32,48
    const int kcol4 = t & 15;
    const int vj0   = (t & 15) * 4;    // V transpose: keys vj0..vj0+3
    const int vf0   = (t >> 4) * 4;    // features vf0..vf0+3
#pragma unroll
    for (int c = 0; c < 4; ++c) {
        kreg[c] = kb4[(krow + 16 * c) * 16 + kcol4];
        vreg[c] = vb4[(vj0 + c) * 16 + (vf0 >> 2)];
    }

    for (int tile = 0; tile < SEQ / 64; ++tile) {
        __syncthreads();   // prior tile's LDS readers done
#pragma unroll
        for (int c = 0; c < 4; ++c)    // K: raw bf16 copy
            *(ushort4*)&ks[(krow + 16 * c) * KSTR + kcol4 * 4] = kreg[c];
        {                              // V: 4x4 in-register transpose
            ushort4 w0 = {vreg[0].x, vreg[1].x, vreg[2].x, vreg[3].x};
            ushort4 w1 = {vreg[0].y, vreg[1].y, vreg[2].y, vreg[3].y};
            ushort4 w2 = {vreg[0].z, vreg[1].z, vreg[2].z, vreg[3].z};
            ushort4 w3 = {vreg[0].w, vreg[1].w, vreg[2].w, vreg[3].w};
            *(ushort4*)&vt[(vf0 + 0) * KSTR + vj0] = w0;
            *(ushort4*)&vt[(vf0 + 1) * KSTR + vj0] = w1;
            *(ushort4*)&vt[(vf0 + 2) * KSTR + vj0] = w2;
            *(ushort4*)&vt[(vf0 + 3) * KSTR + vj0] = w3;
        }
        __syncthreads();   // staging visible

        if (tile + 1 < SEQ / 64) {     // prefetch next tile (latency hidden by compute)
#pragma unroll
            for (int c = 0; c < 4; ++c) {
                kreg[c] = kb4[(tile + 1) * 1024 + (krow + 16 * c) * 16 + kcol4];
                vreg[c] = vb4[(tile + 1) * 1024 + (vj0 + c) * 16 + (vf0 >> 2)];
            }
        }

        // ---- QK^T: 4 key-subtiles x 2 d-chunks ----
        f32x4 S[4];
#pragma unroll
        for (int T = 0; T < 4; ++T) {
            const u16* kp = &ks[(16 * T + m15) * KSTR + quad * 8];
            short8 kb0 = *(const short8*)kp;
            short8 kb1 = *(const short8*)(kp + 32);
            S[T] = MFMA16(qa0, kb0, ((f32x4){0.f, 0.f, 0.f, 0.f}));
            S[T] = MFMA16(qa1, kb1, S[T]);
        }

        // ---- online softmax (rows 4*quad+r live in this quad) ----
        float mx[4], alpha[4], mn[4], psum[4];
#pragma unroll
        for (int T = 0; T < 4; ++T)
#pragma unroll
            for (int r = 0; r < 4; ++r) S[T][r] *= 0.125f;   // 1/sqrt(64)
#pragma unroll
        for (int r = 0; r < 4; ++r) {
            mx[r] = fmaxf(fmaxf(S[0][r], S[1][r]), fmaxf(S[2][r], S[3][r]));
#pragma unroll
            for (int s = 1; s < 16; s <<= 1) mx[r] = fmaxf(mx[r], __shfl_xor(mx[r], s));
            mn[r] = fmaxf(mrow[r], mx[r]);
            alpha[r] = __expf(mrow[r] - mn[r]);
            mrow[r] = mn[r];
            psum[r] = 0.f;
        }
#pragma unroll
        for (int T = 0; T < 4; ++T)
#pragma unroll
            for (int r = 0; r < 4; ++r) {
                float p = __expf(S[T][r] - mn[r]);
                psum[r] += p;
                ps[w][(4 * quad + r) * KSTR + 16 * T + m15] = f2bf(p);
            }
#pragma unroll
        for (int r = 0; r < 4; ++r) {
#pragma unroll
            for (int s = 1; s < 16; s <<= 1) psum[r] += __shfl_xor(psum[r], s);
            lrow[r] = lrow[r] * alpha[r] + psum[r];
        }
#pragma unroll
        for (int F = 0; F < 4; ++F)
#pragma unroll
            for (int r = 0; r < 4; ++r) accO[F][r] *= alpha[r];

        // ---- PV: A = P (same-wave region, no barrier needed), B = Vt ----
        const u16* pp = &ps[w][m15 * KSTR + quad * 8];
        short8 pa0 = *(const short8*)pp;          // keys 0..31
        short8 pa1 = *(const short8*)(pp + 32);   // keys 32..63
#pragma unroll
        for (int F = 0; F < 4; ++F) {
            const u16* vp = &vt[(16 * F + m15) * KSTR + quad * 8];
            short8 vb0 = *(const short8*)vp;
            short8 vb1 = *(const short8*)(vp + 32);
            accO[F] = MFMA16(pa0, vb0, accO[F]);
            accO[F] = MFMA16(pa1, vb1, accO[F]);
        }
    }

    // ---- epilogue: normalize + fp32 store ----
    float il[4];
#pragma unroll
    for (int r = 0; r < 4; ++r) il[r] = 1.f / lrow[r];
#pragma unroll
    for (int F = 0; F < 4; ++F)
#pragma unroll
        for (int r = 0; r < 4; ++r)
            out[((long)(b * SEQ + q0 + 16 * w + 4 * quad + r)) * DF + 16 * F + m15] =
                accO[F][r] * il[r];
}

extern "C" void kernel_launch(void* const* d_in, const int* in_sizes, int n_in,
                              void* d_out, int out_size, void* d_ws, size_t ws_size,
                              hipStream_t stream) {
    (void)in_sizes; (void)n_in; (void)out_size; (void)ws_size;

    const float* X[3]  = { (const float*)d_in[0], (const float*)d_in[1], (const float*)d_in[2] };
    const float* W[3]  = { (const float*)d_in[3], (const float*)d_in[5], (const float*)d_in[7] };
    const float* Bv[3] = { (const float*)d_in[4], (const float*)d_in[6], (const float*)d_in[8] };

    u16* ws = (u16*)d_ws;
    const size_t proj_elems = (size_t)NB * SEQ * DF;   // 1,048,576
    u16* P[3] = { ws, ws + proj_elems, ws + 2 * proj_elems };  // Q, K, V (bf16)
    float* out = (float*)d_out;

    for (int i = 0; i < 3; ++i)
        proj2_kernel<<<(NB * SEQ) / 64, 256, 0, stream>>>(X[i], W[i], Bv[i], P[i]);

    dim3 agrid(SEQ / 64, NB);
    attn_mfma_kernel<<<agrid, 256, 0, stream>>>(P[0], P[1], P[2], out);
}